// Round 10
// baseline (4731.951 us; speedup 1.0000x reference)
//
#include <hip/hip_runtime.h>

// LGA3: 3 chained local-guided-aggregation passes, rolling-accumulator stencil.
// d-split variant: each 256-thread block (64w x 4 d-groups) owns 32 of the 64
// disparities -> 2304 small blocks, ~4 resident/CU, independent barrier groups
// to hide weight-load latency. Cost planes in double-buffered write-once LDS
// (global_load_lds, 34-plane tile); padding enforced by register masking only
// on edge blocks/waves. Weights batch-loaded per iteration (uniform row bases).
// cost [B=2, D=64, H=384, W=768] fp32, weights [B, 75, H, W] fp32.
// out[b,d,h,w] = sum_{i,j in 5x5} w0*c[d-1,h+i-2,w+j-2] + w1*c[d,..] + w2*c[d+1,..]

#define B_ 2
#define D_ 64
#define H_ 384
#define W_ 768
static constexpr int HW    = H_ * W_;
static constexpr int DPT   = 8;          // disparities per thread
static constexpr int NTY   = 4;          // 4 waves/block -> 32 d per block
static constexpr int WT    = 64;
static constexpr int HSEG  = 8;          // output rows per block
static constexpr int RITER = HSEG + 4;   // 12 streamed input rows
static constexpr int LROW  = 72;         // floats per LDS plane row (288 B)
static constexpr int LRWS  = 34;         // LDS rows: planes dbase..dbase+33
static constexpr int NGRAN = LRWS * 18;  // 612 granules of 16 B per stage
static constexpr int NCH   = 10;         // ceil(612/64) 1-KiB chunks
static constexpr int LBUF  = NCH * 256;  // 2560 floats per buffer (chunk 9 slack)

__device__ __forceinline__ void gld_lds16(const float* g, float* l) {
  __builtin_amdgcn_global_load_lds((const __attribute__((address_space(1))) unsigned int*)g,
                                   (__attribute__((address_space(3))) unsigned int*)l,
                                   16, 0, 0);
}

__global__ __launch_bounds__(256, 4) void lga_pass(const float* __restrict__ src,
                                                   const float* __restrict__ wts,
                                                   float* __restrict__ dst) {
  __shared__ float cl[2][LBUF];           // 20480 B total; write-once per buffer

  const int tx    = threadIdx.x;          // 0..63 (lane; wave = ty)
  const int ty    = threadIdx.y;          // 0..3
  const int bx    = blockIdx.x;
  const int w0    = bx * WT, w = w0 + tx;
  const int hs    = blockIdx.y * HSEG;
  const int b     = blockIdx.z >> 1;
  const int dhalf = blockIdx.z & 1;
  const int dbase = dhalf * 32 - 1;       // plane held in LDS row 0
  const int d0    = dhalf * 32 + ty * DPT;

  const float* sb  = src + (size_t)b * D_ * HW;
  const float* wtb = wts + (size_t)b * 75 * HW;

  const bool has_lo = (d0 > 0);
  const bool has_hi = (d0 + DPT < D_);
  const bool edge   = (bx == 0) || (bx == W_ / WT - 1);

  // stage one input row: LDS rows 0..33 <- planes clamp(dbase+p, 0, 63)
  auto stage = [&](int buf, int h_in) {
#pragma unroll
    for (int q = 0; q < 3; ++q) {
      const int c = ty + q * 4;                     // wave-uniform chunk id
      if (c < NCH) {
        int G = c * 64 + tx;                        // granule id
        G = G > NGRAN - 1 ? NGRAN - 1 : G;          // clamp tail (slack area)
        const int p  = G / 18;                      // LDS row
        const int k  = G - p * 18;                  // granule within row
        int pd = dbase + p;                         // source plane
        pd = pd < 0 ? 0 : (pd > D_ - 1 ? D_ - 1 : pd);
        long idx = (long)pd * HW + (long)h_in * W_ + (w0 - 4) + (k << 2);
        idx = idx < 0 ? 0 : idx;
        const long mx = (long)D_ * HW - 4;
        idx = idx > mx ? mx : idx;
        gld_lds16(sb + idx, &cl[buf][c * 256]);
      }
    }
  };

  // prologue: stage input row hs-2 into buf 0
  {
    const int h0 = hs - 2;
    if (h0 >= 0) stage(0, h0);
  }
  __syncthreads();

  float acc[5][DPT];
#pragma unroll
  for (int s = 0; s < 5; ++s)
#pragma unroll
    for (int k = 0; k < DPT; ++k) acc[s][k] = 0.f;

  int n = 0;
#pragma unroll 1
  for (int r = 0; r < RITER; ++r) {
    // ---- 1. batch weight prefetch: all 75 loads, slot order (earliest use first)
    float W[75];
#pragma unroll
    for (int s = 0; s < 5; ++s) {
      if ((unsigned)(r - 4 + s) < (unsigned)HSEG) {       // wave-uniform
        const int o     = hs + r - 4 + s;
        const int ib    = (4 - s) * 5;
        const float* wr = wtb + (size_t)o * W_;           // uniform row base
#pragma unroll
        for (int g = 0; g < 3; ++g)
#pragma unroll
          for (int j = 0; j < 5; ++j)
            W[s * 15 + g * 5 + j] = wr[(size_t)(ib + j + 25 * g) * HW + w];
      }
    }

    // ---- 2. async stage of next input row into the other buffer
    if (r + 1 < RITER) {
      const int h_nx = hs - 2 + r + 1;
      if ((unsigned)h_nx < (unsigned)H_) stage(n ^ 1, h_nx);
    }

    // ---- 3. LDS -> vv; padding masks only where needed (edge blocks / d-edge waves)
    const int  h_in = hs - 2 + r;
    const bool hv   = (unsigned)h_in < (unsigned)H_;      // wave-uniform
    float vv[5][DPT + 2];
    if (hv) {
      const float* vbase = cl[n] + ty * DPT * LROW + tx + 2;
      if (!edge) {                                        // interior: no lane masks
#pragma unroll
        for (int j = 0; j < 5; ++j)
#pragma unroll
          for (int m = 0; m < DPT + 2; ++m)
            vv[j][m] = vbase[m * LROW + j];
        if (!has_lo) {                                    // uniform wave branch
#pragma unroll
          for (int j = 0; j < 5; ++j) vv[j][0] = 0.f;
        }
        if (!has_hi) {
#pragma unroll
          for (int j = 0; j < 5; ++j) vv[j][DPT + 1] = 0.f;
        }
      } else {
#pragma unroll
        for (int j = 0; j < 5; ++j) {
          const bool wokj = (unsigned)(w + j - 2) < (unsigned)W_;
#pragma unroll
          for (int m = 0; m < DPT + 2; ++m) {
            const float v = vbase[m * LROW + j];
            bool ok = wokj;
            if (m == 0)       ok = ok && has_lo;
            if (m == DPT + 1) ok = ok && has_hi;
            vv[j][m] = ok ? v : 0.f;
          }
        }
      }
    }

    // ---- 4. per-slot FMAs (slot s -> output row hs+r-4+s, tap row 4-s)
#pragma unroll
    for (int s = 0; s < 5; ++s) {
      if (hv && (unsigned)(r - 4 + s) < (unsigned)HSEG) {
#pragma unroll
        for (int j = 0; j < 5; ++j)
#pragma unroll
          for (int k = 0; k < DPT; ++k)
            acc[s][k] = fmaf(W[s * 15 + j],      vv[j][k],
                        fmaf(W[s * 15 + 5 + j],  vv[j][k + 1],
                        fmaf(W[s * 15 + 10 + j], vv[j][k + 2], acc[s][k])));
      }
    }

    // ---- 5. slot 0 complete -> write output row hs+r-4
    if (r >= 4) {
      const int o = hs + r - 4;
#pragma unroll
      for (int k = 0; k < DPT; ++k) {
        float* dp = dst + (((size_t)b * D_ + d0 + k) * H_ + o) * W_;
        dp[w] = acc[0][k];
      }
    }

    // ---- 6. rotate accumulator slots (static indices)
#pragma unroll
    for (int s = 0; s < 4; ++s)
#pragma unroll
      for (int k = 0; k < DPT; ++k) acc[s][k] = acc[s + 1][k];
#pragma unroll
    for (int k = 0; k < DPT; ++k) acc[4][k] = 0.f;

    __syncthreads();   // drains staged loads; swap buffers
    n ^= 1;
  }
}

extern "C" void kernel_launch(void* const* d_in, const int* in_sizes, int n_in,
                              void* d_out, int out_size, void* d_ws, size_t ws_size,
                              hipStream_t stream) {
  const float* cost = (const float*)d_in[0];
  const float* wts  = (const float*)d_in[1];
  float* out = (float*)d_out;
  float* ws  = (float*)d_ws;

  dim3 grid(W_ / WT, H_ / HSEG, B_ * 2);   // 12 x 48 x 4 = 2304 blocks
  dim3 block(WT, NTY);                     // 64 x 4 = 256 threads

  lga_pass<<<grid, block, 0, stream>>>(cost, wts, out);
  lga_pass<<<grid, block, 0, stream>>>(out, wts, ws);
  lga_pass<<<grid, block, 0, stream>>>(ws, wts, out);
}

// Round 11
// 634.766 us; speedup vs baseline: 7.4546x; 7.4546x over previous
//
#include <hip/hip_runtime.h>

// LGA3: 3 chained local-guided-aggregation passes, rolling-accumulator stencil.
// R9 shell + weights staged to LDS: per iteration, the exact 75-channel x 64-w
// weight slice is async-staged (global_load_lds, double-buffered) ONCE per block
// and consumed by all 8 d-waves as imm-offset ds_reads. Cost planes in
// double-buffered write-once LDS; d-pad planes zeroed once in the prologue;
// w-edge masking only on edge blocks (wave-uniform branch).
// cost [B=2, D=64, H=384, W=768] fp32, weights [B, 75, H, W] fp32.
// out[b,d,h,w] = sum_{i,j in 5x5} w0*c[d-1,h+i-2,w+j-2] + w1*c[d,..] + w2*c[d+1,..]

#define B_ 2
#define D_ 64
#define H_ 384
#define W_ 768
static constexpr int HW    = H_ * W_;
static constexpr int DPT   = 8;          // disparities per thread
static constexpr int NTY   = D_ / DPT;   // 8 waves
static constexpr int WT    = 64;
static constexpr int HSEG  = 8;          // output rows per block
static constexpr int RITER = HSEG + 4;   // 12 streamed input rows
static constexpr int LROW  = 72;         // floats per cost plane row (288 B)
static constexpr int LPL   = 66;         // row 0 = zero(d=-1), 1..64 = planes, 65 = zero(d=64)
static constexpr int NCH_C = 18;         // 1 KiB chunks per cost-row stage
static constexpr int NCH_W = 19;         // 1 KiB chunks per weight stage
static constexpr int WCH   = 76;         // padded weight channels in LDS (75 + 1 dup)

__device__ __forceinline__ void gld_lds16(const float* g, float* l) {
  __builtin_amdgcn_global_load_lds((const __attribute__((address_space(1))) unsigned int*)g,
                                   (__attribute__((address_space(3))) unsigned int*)l,
                                   16, 0, 0);
}

__global__ __launch_bounds__(512, 1) void lga_pass(const float* __restrict__ src,
                                                   const float* __restrict__ wts,
                                                   float* __restrict__ dst) {
  __shared__ float cl[2][LPL * LROW];     // 38016 B cost tiles (write-once per buffer)
  __shared__ float wl[2][WCH * 64];       // 38912 B weight slices

  const int tx = threadIdx.x;             // 0..63 (lane; wave = ty)
  const int ty = threadIdx.y;             // 0..7
  const int bx = blockIdx.x;
  const int w0 = bx * WT, w = w0 + tx;
  const int hs = blockIdx.y * HSEG;
  const int b  = blockIdx.z;
  const int d0 = ty * DPT;

  const float* sb  = src + (size_t)b * D_ * HW;
  const float* wtb = wts + (size_t)b * 75 * HW;

  const bool edge = (bx == 0) || (bx == W_ / WT - 1);

  // ---- stage one cost row (64 planes x 288 B) into buffer `buf`, rows 1..64
  auto stage_c = [&](int buf, int h_in) {
#pragma unroll
    for (int q = 0; q < 3; ++q) {
      const int c = ty + q * 8;                    // wave-uniform chunk id
      if (c < NCH_C) {
        const int G = c * 64 + tx;
        const int d = G / NCH_C;
        const int k = G - d * NCH_C;
        long idx = (long)d * HW + (long)h_in * W_ + (w0 - 4) + (k << 2);
        idx = idx < 0 ? 0 : idx;
        const long mx = (long)D_ * HW - 4;
        idx = idx > mx ? mx : idx;
        gld_lds16(sb + idx, &cl[buf][LROW + c * 256]);
      }
    }
  };

  // ---- stage the 75 weight channels iteration `rr` consumes:
  // LDS channel ch = s*15 + g*5 + j  <-  weights[b][(4-s)*5+j+25g][hs+rr-4+s][w0..w0+63]
  auto stage_w = [&](int buf, int rr) {
#pragma unroll
    for (int q = 0; q < 3; ++q) {
      const int ci = ty + q * 8;                   // wave-uniform chunk id
      if (ci < NCH_W) {
        int ch = ci * 4 + (tx >> 4);
        ch = ch > 74 ? 74 : ch;                    // channel 75 = dup pad, never read
        const int s  = ch / 15;
        const int t  = ch - s * 15;
        const int g  = t / 5;
        const int j  = t - g * 5;
        const int cw = (4 - s) * 5 + j + g * 25;
        int o = hs + rr - 4 + s;
        o = o < 0 ? 0 : (o >= H_ ? H_ - 1 : o);    // clamped rows never consumed
        const float* p = wtb + (size_t)cw * HW + (size_t)o * W_ + w0 + ((tx & 15) << 2);
        gld_lds16(p, &wl[buf][ci * 256]);
      }
    }
  };

  // ---- one-time zero of the d-pad planes (rows 0 and 65 of both cost buffers);
  // these rows are never written again -> no write/read aliasing in the loop.
  {
    const int flat = ty * WT + tx;                 // 0..511
    if (flat < 2 * 2 * LROW) {                     // 288 entries
      const int q   = flat / (2 * LROW);
      const int rem = flat - q * (2 * LROW);
      const int row = (rem >= LROW) ? (LPL - 1) : 0;
      const int col = (rem >= LROW) ? rem - LROW : rem;
      cl[q][row * LROW + col] = 0.f;
    }
  }

  // prologue: stage iteration 0 into buffer 0
  {
    const int h0 = hs - 2;
    if (h0 >= 0) stage_c(0, h0);
    stage_w(0, 0);
  }
  __syncthreads();

  float acc[5][DPT];
#pragma unroll
  for (int s = 0; s < 5; ++s)
#pragma unroll
    for (int k = 0; k < DPT; ++k) acc[s][k] = 0.f;

  int n = 0;
#pragma unroll 1
  for (int r = 0; r < RITER; ++r) {
    // ---- 1. async stage of iteration r+1 (cost row + weight slice)
    if (r + 1 < RITER) {
      const int h_nx = hs - 2 + r + 1;
      if ((unsigned)h_nx < (unsigned)H_) stage_c(n ^ 1, h_nx);
      stage_w(n ^ 1, r + 1);
    }

    // ---- 2. LDS -> vv (d-pads come from the zeroed rows; w-masks only on edge)
    const int  h_in = hs - 2 + r;
    const bool hv   = (unsigned)h_in < (unsigned)H_;      // wave-uniform
    float vv[5][DPT + 2];
    if (hv) {
      const float* vbase = cl[n] + d0 * LROW + tx + 2;
      if (!edge) {
#pragma unroll
        for (int j = 0; j < 5; ++j)
#pragma unroll
          for (int m = 0; m < DPT + 2; ++m)
            vv[j][m] = vbase[m * LROW + j];
      } else {
#pragma unroll
        for (int j = 0; j < 5; ++j) {
          const bool wokj = (unsigned)(w + j - 2) < (unsigned)W_;
#pragma unroll
          for (int m = 0; m < DPT + 2; ++m) {
            const float v = vbase[m * LROW + j];
            vv[j][m] = wokj ? v : 0.f;
          }
        }
      }
    }

    // ---- 3. per-slot: 15 weight ds_reads (imm offsets) + 120 FMAs
    const float* wcur = wl[n];
#pragma unroll
    for (int s = 0; s < 5; ++s) {
      if (hv && (unsigned)(r - 4 + s) < (unsigned)HSEG) { // wave-uniform
        const float* wsl = wcur + s * 15 * 64 + tx;
#pragma unroll
        for (int j = 0; j < 5; ++j) {
          const float w0v = wsl[(j)      * 64];
          const float w1v = wsl[(5 + j)  * 64];
          const float w2v = wsl[(10 + j) * 64];
#pragma unroll
          for (int k = 0; k < DPT; ++k)
            acc[s][k] = fmaf(w0v, vv[j][k],
                        fmaf(w1v, vv[j][k + 1],
                        fmaf(w2v, vv[j][k + 2], acc[s][k])));
        }
      }
    }

    // ---- 4. slot 0 complete -> write output row hs+r-4
    if (r >= 4) {
      const int o = hs + r - 4;
#pragma unroll
      for (int k = 0; k < DPT; ++k) {
        float* dp = dst + (((size_t)b * D_ + d0 + k) * H_ + o) * W_;
        dp[w] = acc[0][k];
      }
    }

    // ---- 5. rotate accumulator slots (static indices)
#pragma unroll
    for (int s = 0; s < 4; ++s)
#pragma unroll
      for (int k = 0; k < DPT; ++k) acc[s][k] = acc[s + 1][k];
#pragma unroll
    for (int k = 0; k < DPT; ++k) acc[4][k] = 0.f;

    __syncthreads();   // drains staged loads (vmcnt) for all waves; swap buffers
    n ^= 1;
  }
}

extern "C" void kernel_launch(void* const* d_in, const int* in_sizes, int n_in,
                              void* d_out, int out_size, void* d_ws, size_t ws_size,
                              hipStream_t stream) {
  const float* cost = (const float*)d_in[0];
  const float* wts  = (const float*)d_in[1];
  float* out = (float*)d_out;
  float* ws  = (float*)d_ws;

  dim3 grid(W_ / WT, H_ / HSEG, B_);   // 12 x 48 x 2 = 1152 blocks
  dim3 block(WT, NTY);                 // 64 x 8 = 512 threads

  lga_pass<<<grid, block, 0, stream>>>(cost, wts, out);
  lga_pass<<<grid, block, 0, stream>>>(out, wts, ws);
  lga_pass<<<grid, block, 0, stream>>>(ws, wts, out);
}